// Round 8
// baseline (400.483 us; speedup 1.0000x reference)
//
#include <hip/hip_runtime.h>
#include <math.h>

#define Bn 16
#define Cn 3
#define Hn 512
#define Wn 512
#define HWn (Hn*Wn)          // 262144
#define CHWn (Cn*HWn)        // 786432
#define Rr 4                 // rows per strip
#define NBLK 512             // persistent grid; capacity 1024 @128VGPR -> 2x margin

__device__ __forceinline__ float clamp01(float x) {
    return fminf(fmaxf(x, 0.0f), 1.0f);
}

// ---------------------------------------------------------------------------
// R4's measured-best sobel strip body (98.6us, VGPR 92, zero scratch) verbatim:
// 54 individually named window scalars, guarded row loads, separate color
// pass (L2/LLC hits). Only change: moff passed in (mean read hoisted).
// ---------------------------------------------------------------------------

#define DECL_SLOT(S)                                                          \
    float wf##S##_0, wf##S##_1, wf##S##_2, wf##S##_3, wf##S##_4, wf##S##_5;   \
    float wv##S##_0, wv##S##_1, wv##S##_2, wv##S##_3, wv##S##_4, wv##S##_5;   \
    float wi##S##_0, wi##S##_1, wi##S##_2, wi##S##_3, wi##S##_4, wi##S##_5;

#define LOAD_ROW(Y, S)                                                        \
    do {                                                                      \
        const int y_ = (Y);                                                   \
        if ((unsigned)y_ < (unsigned)Hn) {                                    \
            const size_t o = (size_t)y_ * Wn + x0;                            \
            float4 o4 = *(const float4*)(o_ + o);                             \
            float4 m4 = *(const float4*)(m_ + o);                             \
            float4 v4 = *(const float4*)(v_ + o);                             \
            float4 i4 = *(const float4*)(i_ + o);                             \
            float oL = 0.f, mL = 0.f, vL = 0.f, iL = 0.f;                     \
            float oR = 0.f, mR = 0.f, vR = 0.f, iR = 0.f;                     \
            if (x0 > 0)      { oL = o_[o - 1]; mL = m_[o - 1];                \
                               vL = v_[o - 1]; iL = i_[o - 1]; }              \
            if (x0 + 4 < Wn) { oR = o_[o + 4]; mR = m_[o + 4];                \
                               vR = v_[o + 4]; iR = i_[o + 4]; }              \
            wf##S##_0 = oL * mL;     wf##S##_1 = o4.x * m4.x;                 \
            wf##S##_2 = o4.y * m4.y; wf##S##_3 = o4.z * m4.z;                 \
            wf##S##_4 = o4.w * m4.w; wf##S##_5 = oR * mR;                     \
            wv##S##_0 = clamp01(sqrtf(vL));   wv##S##_1 = clamp01(sqrtf(v4.x)); \
            wv##S##_2 = clamp01(sqrtf(v4.y)); wv##S##_3 = clamp01(sqrtf(v4.z)); \
            wv##S##_4 = clamp01(sqrtf(v4.w)); wv##S##_5 = clamp01(sqrtf(vR));   \
            wi##S##_0 = clamp01(fmaf(1.8f, iL,   -moff));                     \
            wi##S##_1 = clamp01(fmaf(1.8f, i4.x, -moff));                     \
            wi##S##_2 = clamp01(fmaf(1.8f, i4.y, -moff));                     \
            wi##S##_3 = clamp01(fmaf(1.8f, i4.z, -moff));                     \
            wi##S##_4 = clamp01(fmaf(1.8f, i4.w, -moff));                     \
            wi##S##_5 = clamp01(fmaf(1.8f, iR,   -moff));                     \
            if (x0 == 0)      { wf##S##_0 = 0.f; wv##S##_0 = 0.f; wi##S##_0 = 0.f; } \
            if (x0 + 4 >= Wn) { wf##S##_5 = 0.f; wv##S##_5 = 0.f; wi##S##_5 = 0.f; } \
        } else {                                                              \
            wf##S##_0=0.f; wf##S##_1=0.f; wf##S##_2=0.f;                      \
            wf##S##_3=0.f; wf##S##_4=0.f; wf##S##_5=0.f;                      \
            wv##S##_0=0.f; wv##S##_1=0.f; wv##S##_2=0.f;                      \
            wv##S##_3=0.f; wv##S##_4=0.f; wv##S##_5=0.f;                      \
            wi##S##_0=0.f; wi##S##_1=0.f; wi##S##_2=0.f;                      \
            wi##S##_3=0.f; wi##S##_4=0.f; wi##S##_5=0.f;                      \
        }                                                                     \
    } while (0)

// cross-correlation (XLA conv): no kernel flip. A = row y-1, B = y, C = y+1.
#define SOBEL_J(A, B, C, J0, J1, J2)                                          \
    do {                                                                      \
        float gxf = (wf##A##_##J2 - wf##A##_##J0) + 2.f * (wf##B##_##J2 - wf##B##_##J0) + (wf##C##_##J2 - wf##C##_##J0); \
        float gyf = (wf##A##_##J0 + 2.f * wf##A##_##J1 + wf##A##_##J2) - (wf##C##_##J0 + 2.f * wf##C##_##J1 + wf##C##_##J2); \
        float gxv = (wv##A##_##J2 - wv##A##_##J0) + 2.f * (wv##B##_##J2 - wv##B##_##J0) + (wv##C##_##J2 - wv##C##_##J0); \
        float gyv = (wv##A##_##J0 + 2.f * wv##A##_##J1 + wv##A##_##J2) - (wv##C##_##J0 + 2.f * wv##C##_##J1 + wv##C##_##J2); \
        float gxi = (wi##A##_##J2 - wi##A##_##J0) + 2.f * (wi##B##_##J2 - wi##B##_##J0) + (wi##C##_##J2 - wi##C##_##J0); \
        float gyi = (wi##A##_##J0 + 2.f * wi##A##_##J1 + wi##A##_##J2) - (wi##C##_##J0 + 2.f * wi##C##_##J1 + wi##C##_##J2); \
        gxA  += fabsf(gxf - fmaxf(gxv, gxi));                                 \
        gyA  += fabsf(gyf - fmaxf(gyv, gyi));                                 \
        conA += fabsf(wf##B##_##J1 - fmaxf(wv##B##_##J1, wi##B##_##J1));      \
    } while (0)

#define STEP(A, B, C)                                                         \
    SOBEL_J(A, B, C, 0, 1, 2); SOBEL_J(A, B, C, 1, 2, 3);                     \
    SOBEL_J(A, B, C, 2, 3, 4); SOBEL_J(A, B, C, 3, 4, 5)

__device__ __forceinline__ void strip_body(
        const float* __restrict__ pv, const float* __restrict__ pi,
        const float* __restrict__ po, const float* __restrict__ pm,
        int y0, int x0, float moff,
        float& conA, float& gxA, float& gyA, float& crA, float& cbA)
{
    // ---------------- per-channel sobel + intensity pass ----------------
    for (int c = 0; c < 3; ++c) {
        const float* v_ = pv + (size_t)c * HWn;
        const float* i_ = pi + (size_t)c * HWn;
        const float* o_ = po + (size_t)c * HWn;
        const float* m_ = pm + (size_t)c * HWn;

        DECL_SLOT(0) DECL_SLOT(1) DECL_SLOT(2)

        LOAD_ROW(y0 - 1, 0);                  // slot0 = row y0-1
        LOAD_ROW(y0,     1);                  // slot1 = row y0
        LOAD_ROW(y0 + 1, 2); STEP(0, 1, 2);   // out row y0
        LOAD_ROW(y0 + 2, 0); STEP(1, 2, 0);   // out row y0+1
        LOAD_ROW(y0 + 3, 1); STEP(2, 0, 1);   // out row y0+2
        LOAD_ROW(y0 + 4, 2); STEP(0, 1, 2);   // out row y0+3
    }

    // ---------------- color pass (center pixels, all 3 channels) ------------
    // Re-reads 9 planes of the strip just touched -> L2/LLC hits.
    for (int y = y0; y < y0 + Rr; ++y) {
        size_t o = (size_t)y * Wn + x0;
        float4 oR = *(const float4*)(po + o);
        float4 oG = *(const float4*)(po + HWn + o);
        float4 oB = *(const float4*)(po + 2 * HWn + o);
        float4 mR = *(const float4*)(pm + o);
        float4 mG = *(const float4*)(pm + HWn + o);
        float4 mB = *(const float4*)(pm + 2 * HWn + o);
        float4 vR = *(const float4*)(pv + o);
        float4 vG = *(const float4*)(pv + HWn + o);
        float4 vB = *(const float4*)(pv + 2 * HWn + o);
#define COLOR_PX(FR, FG, FB, VR, VG, VB)                                      \
        do {                                                                  \
            float fr = (FR), fg = (FG), fb = (FB);                            \
            float vr = (VR), vg = (VG), vb = (VB);                            \
            float fY = 0.299f * fr + 0.587f * fg + 0.114f * fb;               \
            float vY = 0.299f * vr + 0.587f * vg + 0.114f * vb;               \
            crA += fabsf((fr - fY) * 0.713f - (vr - vY) * 0.713f);            \
            cbA += fabsf((fb - fY) * 0.564f - (vb - vY) * 0.564f);            \
        } while (0)
        COLOR_PX(oR.x * mR.x, oG.x * mG.x, oB.x * mB.x,
                 clamp01(sqrtf(vR.x)), clamp01(sqrtf(vG.x)), clamp01(sqrtf(vB.x)));
        COLOR_PX(oR.y * mR.y, oG.y * mG.y, oB.y * mB.y,
                 clamp01(sqrtf(vR.y)), clamp01(sqrtf(vG.y)), clamp01(sqrtf(vB.y)));
        COLOR_PX(oR.z * mR.z, oG.z * mG.z, oB.z * mB.z,
                 clamp01(sqrtf(vR.z)), clamp01(sqrtf(vG.z)), clamp01(sqrtf(vB.z)));
        COLOR_PX(oR.w * mR.w, oG.w * mG.w, oB.w * mB.w,
                 clamp01(sqrtf(vR.w)), clamp01(sqrtf(vG.w)), clamp01(sqrtf(vB.w)));
#undef COLOR_PX
    }
}

// ---------------------------------------------------------------------------
// Single persistent kernel: phase1 gray-mean -> device barrier -> phase2 main
// (2 strip-jobs/block) -> last-block finalize. NBLK=512 blocks, 256 thr,
// launch_bounds(256,4) caps VGPR at 128 -> >=4 blocks/CU capacity (1024) so
// all 512 are co-resident: the atomic-counter barrier cannot deadlock.
// ws[0..15] per-batch gray sums; ws[16..20] loss sums; wsi[24]/wsi[25]
// barrier/finalize counters (zeroed by the 32-float memset).
// ---------------------------------------------------------------------------
__global__ __launch_bounds__(256, 4) void fused_kernel(
        const float* __restrict__ vis, const float* __restrict__ ir,
        const float* __restrict__ outp, const float* __restrict__ mask,
        float* __restrict__ ws, float* __restrict__ out)
{
    __shared__ float red[5][4];
    const int bid = blockIdx.x;
    const int tid = threadIdx.x;
    int* wsi = (int*)ws;

    // ---------------- phase 1: per-batch gray sums of ir ----------------
    {
        const int gb = bid >> 5;          // batch 0..15
        const int gx = bid & 31;          // 8192-px chunk 0..31
        const float* base = ir + (size_t)gb * CHWn;
        float sr = 0.f, sg = 0.f, sb = 0.f;
#pragma unroll
        for (int k = 0; k < 8; ++k) {
            size_t px = (size_t)gx * 8192 + (size_t)(k * 256 + tid) * 4;
            float4 r4 = *(const float4*)(base + px);
            float4 g4 = *(const float4*)(base + HWn + px);
            float4 b4 = *(const float4*)(base + 2 * HWn + px);
            sr += (r4.x + r4.y) + (r4.z + r4.w);
            sg += (g4.x + g4.y) + (g4.z + g4.w);
            sb += (b4.x + b4.y) + (b4.z + b4.w);
        }
        float s = 0.2989f * sr + 0.587f * sg + 0.114f * sb;
#pragma unroll
        for (int off = 32; off; off >>= 1) s += __shfl_down(s, off, 64);
        if ((tid & 63) == 0) red[0][tid >> 6] = s;
        __syncthreads();
        if (tid == 0) {
            atomicAdd(&ws[gb], (red[0][0] + red[0][1]) + (red[0][2] + red[0][3]));
            __threadfence();                       // ws[gb] visible before signal
            atomicAdd(&wsi[24], 1);
            while (__hip_atomic_load(&wsi[24], __ATOMIC_RELAXED,
                                     __HIP_MEMORY_SCOPE_AGENT) < NBLK)
                __builtin_amdgcn_s_sleep(8);
        }
        __syncthreads();                           // release whole block
    }

    // ---------------- phase 2: two strip-jobs per block ----------------
    const int x  = bid & 63;                       // strip-pair 0..63
    const int b1 = bid >> 6;                       // batches 0..7
    const float mean1 = __hip_atomic_load(&ws[b1],     __ATOMIC_RELAXED,
                                          __HIP_MEMORY_SCOPE_AGENT) * (1.0f / (float)HWn);
    const float mean2 = __hip_atomic_load(&ws[b1 + 8], __ATOMIC_RELAXED,
                                          __HIP_MEMORY_SCOPE_AGENT) * (1.0f / (float)HWn);

    const int tx = tid & 127;
    const int sy = tid >> 7;
    const int y0 = (x * 2 + sy) * Rr;
    const int x0 = tx * 4;

    float conA = 0.f, gxA = 0.f, gyA = 0.f, crA = 0.f, cbA = 0.f;

#pragma unroll 1
    for (int jj = 0; jj < 2; ++jj) {
        const int bb_idx = b1 + jj * 8;
        const float moff = 0.8f * (jj ? mean2 : mean1);
        const size_t bb = (size_t)bb_idx * CHWn;
        strip_body(vis + bb, ir + bb, outp + bb, mask + bb,
                   y0, x0, moff, conA, gxA, gyA, crA, cbA);
    }

    // ---------------- block reduction + atomics + last-block finalize ----
    auto wred = [](float v) {
#pragma unroll
        for (int off = 32; off; off >>= 1) v += __shfl_down(v, off, 64);
        return v;
    };
    conA = wred(conA); gxA = wred(gxA); gyA = wred(gyA);
    crA  = wred(crA);  cbA = wred(cbA);

    const int lane = tid & 63, w = tid >> 6;
    __syncthreads();                               // red[] reuse after phase 1
    if (lane == 0) {
        red[0][w] = conA; red[1][w] = gxA; red[2][w] = gyA;
        red[3][w] = crA;  red[4][w] = cbA;
    }
    __syncthreads();
    if (tid == 0) {
#pragma unroll
        for (int r = 0; r < 5; ++r)
            atomicAdd(&ws[16 + r], (red[r][0] + red[r][1]) + (red[r][2] + red[r][3]));
        __threadfence();
        int old = atomicAdd(&wsi[25], 1);
        if (old == NBLK - 1) {                     // last block: all sums visible
            const float invN3 = 1.0f / (float)((size_t)Bn * Cn * HWn);
            const float invN1 = 1.0f / (float)((size_t)Bn * HWn);
            float con = __hip_atomic_load(&ws[16], __ATOMIC_RELAXED, __HIP_MEMORY_SCOPE_AGENT) * invN3;
            float gx  = __hip_atomic_load(&ws[17], __ATOMIC_RELAXED, __HIP_MEMORY_SCOPE_AGENT) * invN3;
            float gy  = __hip_atomic_load(&ws[18], __ATOMIC_RELAXED, __HIP_MEMORY_SCOPE_AGENT) * invN3;
            float cr  = __hip_atomic_load(&ws[19], __ATOMIC_RELAXED, __HIP_MEMORY_SCOPE_AGENT) * invN1;
            float cb  = __hip_atomic_load(&ws[20], __ATOMIC_RELAXED, __HIP_MEMORY_SCOPE_AGENT) * invN1;
            out[0] = 0.5f * con + 0.2f * (0.5f * gx + 0.5f * gy) + (cb + cr);
        }
    }
}

extern "C" void kernel_launch(void* const* d_in, const int* in_sizes, int n_in,
                              void* d_out, int out_size, void* d_ws, size_t ws_size,
                              hipStream_t stream)
{
    const float* vis = (const float*)d_in[0];
    const float* ir  = (const float*)d_in[1];
    const float* out = (const float*)d_in[2];
    const float* msk = (const float*)d_in[3];
    float* ws = (float*)d_ws;

    hipMemsetAsync(ws, 0, 32 * sizeof(float), stream);
    fused_kernel<<<dim3(NBLK), 256, 0, stream>>>(vis, ir, out, msk, ws, (float*)d_out);
}